// Round 2
// baseline (508.002 us; speedup 1.0000x reference)
//
#include <hip/hip_runtime.h>

#define HH 512
#define WW 512
#define BBATCH 2
#define CKXY 0.3125f   /* COMPACT / sqrt(H*W/NSUP) = 10/32 */

// ---------------------------------------------------------------- conv 3x3
template<int CIN, int COUT, bool RELU>
__global__ __launch_bounds__(256) void conv3x3(const float* __restrict__ in,
    const float* __restrict__ w, const float* __restrict__ bias,
    float* __restrict__ out) {
  const int bx = blockIdx.x, by = blockIdx.y, b = blockIdx.z;
  const int tx = threadIdx.x, ty = threadIdx.y;
  const int tid = ty * 16 + tx;
  __shared__ float sIn[CIN][18][18];
  const float* inb = in + (size_t)b * CIN * HH * WW;
  for (int idx = tid; idx < CIN * 324; idx += 256) {
    int ci = idx / 324, rem = idx - ci * 324;
    int ly = rem / 18, lx = rem - ly * 18;
    int gy = by * 16 + ly - 1, gx = bx * 16 + lx - 1;
    float v = 0.f;
    if ((unsigned)gy < HH && (unsigned)gx < WW) v = inb[ci * HH * WW + gy * WW + gx];
    sIn[ci][ly][lx] = v;
  }
  __syncthreads();
  float acc[COUT];
  #pragma unroll
  for (int co = 0; co < COUT; ++co) acc[co] = bias[co];
  #pragma unroll
  for (int ci = 0; ci < CIN; ++ci) {
    float v[9];
    #pragma unroll
    for (int t = 0; t < 9; ++t) v[t] = sIn[ci][ty + t / 3][tx + t % 3];
    #pragma unroll
    for (int co = 0; co < COUT; ++co) {
      #pragma unroll
      for (int t = 0; t < 9; ++t)
        acc[co] = fmaf(v[t], w[(co * CIN + ci) * 9 + t], acc[co]);
    }
  }
  const int gy = by * 16 + ty, gx = bx * 16 + tx;
  float* outb = out + (size_t)b * COUT * HH * WW;
  #pragma unroll
  for (int co = 0; co < COUT; ++co) {
    float r = RELU ? fmaxf(acc[co], 0.f) : acc[co];
    outb[co * HH * WW + gy * WW + gx] = r;
  }
}

// ------------------------------------------- final conv (10->5) + build imfeat'
// imfeat' channels: 0..4 = s1, 5..7 = X, 8 = x*CKXY, 9 = y*CKXY
__global__ __launch_bounds__(256) void conv_final_imfeat(const float* __restrict__ in,
    const float* __restrict__ w, const float* __restrict__ bias,
    const float* __restrict__ X, float* __restrict__ imfeat) {
  const int bx = blockIdx.x, by = blockIdx.y, b = blockIdx.z;
  const int tx = threadIdx.x, ty = threadIdx.y;
  const int tid = ty * 16 + tx;
  __shared__ float sIn[10][18][18];
  const float* inb = in + (size_t)b * 10 * HH * WW;
  for (int idx = tid; idx < 10 * 324; idx += 256) {
    int ci = idx / 324, rem = idx - ci * 324;
    int ly = rem / 18, lx = rem - ly * 18;
    int gy = by * 16 + ly - 1, gx = bx * 16 + lx - 1;
    float v = 0.f;
    if ((unsigned)gy < HH && (unsigned)gx < WW) v = inb[ci * HH * WW + gy * WW + gx];
    sIn[ci][ly][lx] = v;
  }
  __syncthreads();
  float acc[5];
  #pragma unroll
  for (int co = 0; co < 5; ++co) acc[co] = bias[co];
  #pragma unroll
  for (int ci = 0; ci < 10; ++ci) {
    float v[9];
    #pragma unroll
    for (int t = 0; t < 9; ++t) v[t] = sIn[ci][ty + t / 3][tx + t % 3];
    #pragma unroll
    for (int co = 0; co < 5; ++co) {
      #pragma unroll
      for (int t = 0; t < 9; ++t)
        acc[co] = fmaf(v[t], w[(co * 10 + ci) * 9 + t], acc[co]);
    }
  }
  const int gy = by * 16 + ty, gx = bx * 16 + tx;
  float* ob = imfeat + (size_t)b * 10 * HH * WW;
  const float* Xb = X + (size_t)b * 3 * HH * WW;
  const int p = gy * WW + gx;
  #pragma unroll
  for (int co = 0; co < 5; ++co) ob[co * HH * WW + p] = acc[co];
  #pragma unroll
  for (int c = 0; c < 3; ++c) ob[(5 + c) * HH * WW + p] = Xb[c * HH * WW + p];
  ob[8 * HH * WW + p] = (float)gx * CKXY;
  ob[9 * HH * WW + p] = (float)gy * CKXY;
}

// ------------------------------------------------- cent0 = blockmean(imfeat')
__global__ __launch_bounds__(256) void blockmean0(const float* __restrict__ imfeat,
                                                  float* __restrict__ cent) {
  const int cx = blockIdx.x, cy = blockIdx.y, b = blockIdx.z;
  const int tid = threadIdx.x;
  const int col = tid & 31, row0 = tid >> 5;
  float acc[10];
  #pragma unroll
  for (int ch = 0; ch < 10; ++ch) acc[ch] = 0.f;
  for (int p = 0; p < 4; ++p) {
    const int y = cy * 32 + row0 + p * 8;
    const int x = cx * 32 + col;
    #pragma unroll
    for (int ch = 0; ch < 10; ++ch)
      acc[ch] += imfeat[((b * 10 + ch) * HH + y) * WW + x];
  }
  #pragma unroll
  for (int off = 32; off; off >>= 1) {
    #pragma unroll
    for (int ch = 0; ch < 10; ++ch) acc[ch] += __shfl_down(acc[ch], off);
  }
  __shared__ float sPart[4][10];
  const int wave = tid >> 6, lane = tid & 63;
  if (lane == 0) {
    #pragma unroll
    for (int ch = 0; ch < 10; ++ch) sPart[wave][ch] = acc[ch];
  }
  __syncthreads();
  if (tid < 10) {
    float s = sPart[0][tid] + sPart[1][tid] + sPart[2][tid] + sPart[3][tid];
    cent[((b * 10 + tid) * 16 + cy) * 16 + cx] = s * (1.0f / 1024.0f);
  }
}

// ---------------------------------------- one SSN iteration: aff + block sums
__global__ __launch_bounds__(256) void iter_kernel(const float* __restrict__ imfeat,
    const float* __restrict__ cent, float* __restrict__ num_bs,
    float* __restrict__ den_bs, float* __restrict__ aff_out) {
  const int cx = blockIdx.x, cy = blockIdx.y, b = blockIdx.z;
  const int tid = threadIdx.x;
  __shared__ float sc[9][10];
  if (tid < 90) {
    int s = tid / 10, ch = tid - s * 10;
    int dr = s / 3 - 1, dc = s % 3 - 1;
    int r = min(max(cy + dr, 0), 15), c = min(max(cx + dc, 0), 15);
    sc[s][ch] = cent[((b * 10 + ch) * 16 + r) * 16 + c];
  }
  __syncthreads();
  float accN[10];
  #pragma unroll
  for (int ch = 0; ch < 10; ++ch) accN[ch] = 0.f;
  float accD = 0.f;
  const int col = tid & 31, row0 = tid >> 5;
  for (int p = 0; p < 4; ++p) {
    const int y = cy * 32 + row0 + p * 8;
    const int x = cx * 32 + col;
    float f[10];
    #pragma unroll
    for (int ch = 0; ch < 10; ++ch)
      f[ch] = imfeat[((b * 10 + ch) * HH + y) * WW + x];
    float asum = 0.f;
    #pragma unroll
    for (int s = 0; s < 9; ++s) {
      float ss = 0.f;
      #pragma unroll
      for (int ch = 0; ch < 10; ++ch) { float d = f[ch] - sc[s][ch]; ss = fmaf(d, d, ss); }
      float a = __expf(-ss * (1.0f / 1000.0f));
      asum += a;
      if (aff_out) aff_out[((b * 9 + s) * HH + y) * WW + x] = a;
    }
    accD += asum;
    #pragma unroll
    for (int ch = 0; ch < 10; ++ch) accN[ch] = fmaf(f[ch], asum, accN[ch]);
  }
  #pragma unroll
  for (int off = 32; off; off >>= 1) {
    accD += __shfl_down(accD, off);
    #pragma unroll
    for (int ch = 0; ch < 10; ++ch) accN[ch] += __shfl_down(accN[ch], off);
  }
  __shared__ float sPart[4][11];
  const int wave = tid >> 6, lane = tid & 63;
  if (lane == 0) {
    #pragma unroll
    for (int ch = 0; ch < 10; ++ch) sPart[wave][ch] = accN[ch];
    sPart[wave][10] = accD;
  }
  __syncthreads();
  if (tid < 11) {
    float s = sPart[0][tid] + sPart[1][tid] + sPart[2][tid] + sPart[3][tid];
    if (tid < 10) num_bs[((b * 10 + tid) * 16 + cy) * 16 + cx] = s;
    else den_bs[(b * 16 + cy) * 16 + cx] = s;
  }
}

// ------------------------------- cent' = box3(num)/box3(den); optional output
__global__ __launch_bounds__(256) void cent_update(const float* __restrict__ num_bs,
    const float* __restrict__ den_bs, float* __restrict__ cent_out,
    float* __restrict__ out_cent) {
  const int b = blockIdx.x;
  const int tid = threadIdx.x;
  const int cy = tid >> 4, cx = tid & 15;
  float den = 0.f;
  #pragma unroll
  for (int dr = -1; dr <= 1; ++dr)
    #pragma unroll
    for (int dc = -1; dc <= 1; ++dc) {
      int r = cy + dr, c = cx + dc;
      if ((unsigned)r < 16 && (unsigned)c < 16) den += den_bs[(b * 16 + r) * 16 + c];
    }
  #pragma unroll
  for (int ch = 0; ch < 10; ++ch) {
    float num = 0.f;
    #pragma unroll
    for (int dr = -1; dr <= 1; ++dr)
      #pragma unroll
      for (int dc = -1; dc <= 1; ++dc) {
        int r = cy + dr, c = cx + dc;
        if ((unsigned)r < 16 && (unsigned)c < 16)
          num += num_bs[((b * 10 + ch) * 16 + r) * 16 + c];
      }
    float v = num / den;
    cent_out[((b * 10 + ch) * 16 + cy) * 16 + cx] = v;
    if (out_cent) {
      float invck = (ch >= 8) ? (1.0f / CKXY) : 1.0f;
      out_cent[((b * 10 + ch) * 16 + cy) * 16 + cx] = v * invck;
    }
  }
}

// ---------------------------------------------------------------------------
extern "C" void kernel_launch(void* const* d_in, const int* in_sizes, int n_in,
                              void* d_out, int out_size, void* d_ws, size_t ws_size,
                              hipStream_t stream) {
  const float* X      = (const float*)d_in[0];
  const float* w0     = (const float*)d_in[1];
  const float* b0     = (const float*)d_in[2];
  const float* ws_mid = (const float*)d_in[3];
  const float* bs_mid = (const float*)d_in[4];
  const float* wf     = (const float*)d_in[5];
  const float* bf     = (const float*)d_in[6];
  float* out = (float*)d_out;

  const size_t plane = (size_t)BBATCH * 10 * HH * WW;  // 5,242,880 floats
  float* bufA   = (float*)d_ws;
  float* bufB   = bufA + plane;
  float* num_bs = bufB + plane;
  float* den_bs = num_bs + BBATCH * 10 * 16 * 16;
  float* centA  = den_bs + BBATCH * 16 * 16;
  float* centB  = centA + BBATCH * 10 * 16 * 16;

  dim3 cgrid(32, 32, BBATCH), cblk(16, 16);
  conv3x3<3, 10, true><<<cgrid, cblk, 0, stream>>>(X, w0, b0, bufA);
  const float* cur = bufA;
  float* nxt = bufB;
  for (int l = 0; l < 8; ++l) {
    conv3x3<10, 10, true><<<cgrid, cblk, 0, stream>>>(cur, ws_mid + l * 900, bs_mid + l * 10, nxt);
    const float* t = cur; cur = nxt; nxt = (float*)t;
  }
  // cur == bufA here (8 swaps), imfeat built into bufB
  conv_final_imfeat<<<cgrid, cblk, 0, stream>>>(cur, wf, bf, X, bufB);

  dim3 igrid(16, 16, BBATCH);
  blockmean0<<<igrid, 256, 0, stream>>>(bufB, centA);

  float* cc = centA;
  float* cn = centB;
  float* aff_out = out + BBATCH * 10 * 16 * 16;  // cent first (5120), then aff
  for (int k = 0; k < 10; ++k) {
    iter_kernel<<<igrid, 256, 0, stream>>>(bufB, cc, num_bs, den_bs,
                                           (k == 9) ? aff_out : nullptr);
    cent_update<<<dim3(BBATCH), 256, 0, stream>>>(num_bs, den_bs, cn,
                                                  (k == 9) ? out : nullptr);
    float* t = cc; cc = cn; cn = t;
  }
}

// Round 4
// 377.178 us; speedup vs baseline: 1.3469x; 1.3469x over previous
//
#include <hip/hip_runtime.h>

#define HH 512
#define WW 512
#define BB 2
#define CKXY 0.3125f   /* COMPACT / sqrt(H*W/NSUP) = 10/32 */
#define HW (HH*WW)

// ------------------------------------------------------------- conv 3x3, 32x32 tile
// Block: 256 threads = 16x16, each thread computes a 2x2 quadrant-strided set of 4 px.
// LDS tile 34x40 (stride 40 -> uniform 2-way bank access on compute reads = free).
template<int CIN, int COUT, bool RELU>
__global__ __launch_bounds__(256) void conv3x3_t32(const float* __restrict__ in,
    const float* __restrict__ w, const float* __restrict__ bias,
    float* __restrict__ out) {
  const int bx = blockIdx.x, by = blockIdx.y, b = blockIdx.z;
  const int tid = threadIdx.x;
  const int tx = tid & 15, ty = tid >> 4;
  __shared__ float sIn[CIN][34][40];
  const float* inb = in + (size_t)b * CIN * HW;
  const int gy0 = by * 32, gx0 = bx * 32;
  // interior 32x32 per channel: shift-indexed, no bounds check needed
  #pragma unroll
  for (int ci = 0; ci < CIN; ++ci) {
    #pragma unroll
    for (int pass = 0; pass < 4; ++pass) {
      int r = (pass << 3) + (tid >> 5);
      int c = tid & 31;
      sIn[ci][r + 1][c + 1] = inb[ci * HW + (gy0 + r) * WW + gx0 + c];
    }
  }
  // halo ring: 132 elems per channel
  for (int idx = tid; idx < CIN * 132; idx += 256) {
    int ci = idx / 132, rem = idx - ci * 132;
    int ly, lx;
    if (rem < 34)       { ly = 0;  lx = rem; }
    else if (rem < 68)  { ly = 33; lx = rem - 34; }
    else if (rem < 100) { lx = 0;  ly = rem - 68 + 1; }
    else                { lx = 33; ly = rem - 100 + 1; }
    int gy = gy0 + ly - 1, gx = gx0 + lx - 1;
    float v = 0.f;
    if ((unsigned)gy < HH && (unsigned)gx < WW) v = inb[ci * HW + gy * WW + gx];
    sIn[ci][ly][lx] = v;
  }
  __syncthreads();

  float acc[COUT][4];
  #pragma unroll
  for (int co = 0; co < COUT; ++co) {
    float bv = bias[co];
    #pragma unroll
    for (int q = 0; q < 4; ++q) acc[co][q] = bv;
  }
  for (int ci = 0; ci < CIN; ++ci) {
    #pragma unroll
    for (int q = 0; q < 4; ++q) {
      const int r0 = ty + ((q >> 1) << 4), c0 = tx + ((q & 1) << 4);
      float v[9];
      #pragma unroll
      for (int t = 0; t < 9; ++t) v[t] = sIn[ci][r0 + t / 3][c0 + t % 3];
      #pragma unroll
      for (int co = 0; co < COUT; ++co) {
        #pragma unroll
        for (int t = 0; t < 9; ++t)
          acc[co][q] = fmaf(v[t], w[(co * CIN + ci) * 9 + t], acc[co][q]);
      }
    }
  }
  float* outb = out + (size_t)b * COUT * HW;
  #pragma unroll
  for (int co = 0; co < COUT; ++co)
    #pragma unroll
    for (int q = 0; q < 4; ++q) {
      int y = gy0 + ty + ((q >> 1) << 4), x = gx0 + tx + ((q & 1) << 4);
      float r = RELU ? fmaxf(acc[co][q], 0.f) : acc[co][q];
      outb[co * HW + y * WW + x] = r;
    }
}

// ---------------------- final conv (10->5) + imfeat build + cent0 reduction
// One block == one SSN cell (32x32). imfeat channels: 0..4 s1, 5..7 X, 8 x*ck, 9 y*ck
__global__ __launch_bounds__(256) void conv_final_t32(const float* __restrict__ in,
    const float* __restrict__ w, const float* __restrict__ bias,
    const float* __restrict__ X, float* __restrict__ imfeat,
    float* __restrict__ cent0) {
  const int bx = blockIdx.x, by = blockIdx.y, b = blockIdx.z;
  const int tid = threadIdx.x;
  const int tx = tid & 15, ty = tid >> 4;
  __shared__ float sIn[10][34][40];
  const float* inb = in + (size_t)b * 10 * HW;
  const int gy0 = by * 32, gx0 = bx * 32;
  #pragma unroll
  for (int ci = 0; ci < 10; ++ci) {
    #pragma unroll
    for (int pass = 0; pass < 4; ++pass) {
      int r = (pass << 3) + (tid >> 5);
      int c = tid & 31;
      sIn[ci][r + 1][c + 1] = inb[ci * HW + (gy0 + r) * WW + gx0 + c];
    }
  }
  for (int idx = tid; idx < 10 * 132; idx += 256) {
    int ci = idx / 132, rem = idx - ci * 132;
    int ly, lx;
    if (rem < 34)       { ly = 0;  lx = rem; }
    else if (rem < 68)  { ly = 33; lx = rem - 34; }
    else if (rem < 100) { lx = 0;  ly = rem - 68 + 1; }
    else                { lx = 33; ly = rem - 100 + 1; }
    int gy = gy0 + ly - 1, gx = gx0 + lx - 1;
    float v = 0.f;
    if ((unsigned)gy < HH && (unsigned)gx < WW) v = inb[ci * HW + gy * WW + gx];
    sIn[ci][ly][lx] = v;
  }
  __syncthreads();

  float acc[5][4];
  #pragma unroll
  for (int co = 0; co < 5; ++co) {
    float bv = bias[co];
    #pragma unroll
    for (int q = 0; q < 4; ++q) acc[co][q] = bv;
  }
  for (int ci = 0; ci < 10; ++ci) {
    #pragma unroll
    for (int q = 0; q < 4; ++q) {
      const int r0 = ty + ((q >> 1) << 4), c0 = tx + ((q & 1) << 4);
      float v[9];
      #pragma unroll
      for (int t = 0; t < 9; ++t) v[t] = sIn[ci][r0 + t / 3][c0 + t % 3];
      #pragma unroll
      for (int co = 0; co < 5; ++co) {
        #pragma unroll
        for (int t = 0; t < 9; ++t)
          acc[co][q] = fmaf(v[t], w[(co * 10 + ci) * 9 + t], acc[co][q]);
      }
    }
  }
  float* ob = imfeat + (size_t)b * 10 * HW;
  const float* Xb = X + (size_t)b * 3 * HW;
  float cs[10];
  #pragma unroll
  for (int ch = 0; ch < 10; ++ch) cs[ch] = 0.f;
  #pragma unroll
  for (int q = 0; q < 4; ++q) {
    int y = gy0 + ty + ((q >> 1) << 4), x = gx0 + tx + ((q & 1) << 4);
    int p = y * WW + x;
    #pragma unroll
    for (int co = 0; co < 5; ++co) { float v = acc[co][q]; ob[co * HW + p] = v; cs[co] += v; }
    #pragma unroll
    for (int c = 0; c < 3; ++c) { float v = Xb[c * HW + p]; ob[(5 + c) * HW + p] = v; cs[5 + c] += v; }
    float xc = (float)x * CKXY, yc = (float)y * CKXY;
    ob[8 * HW + p] = xc; cs[8] += xc;
    ob[9 * HW + p] = yc; cs[9] += yc;
  }
  #pragma unroll
  for (int off = 32; off; off >>= 1) {
    #pragma unroll
    for (int ch = 0; ch < 10; ++ch) cs[ch] += __shfl_down(cs[ch], off);
  }
  __shared__ float sP[4][10];
  const int wave = tid >> 6;
  if ((tid & 63) == 0) {
    #pragma unroll
    for (int ch = 0; ch < 10; ++ch) sP[wave][ch] = cs[ch];
  }
  __syncthreads();
  if (tid < 10) {
    float s = sP[0][tid] + sP[1][tid] + sP[2][tid] + sP[3][tid];
    cent0[((b * 10 + tid) * 16 + by) * 16 + bx] = s * (1.0f / 1024.0f);
  }
}

// -------------------- SSN iteration: (optional in-block centroid) + aff + sums
__global__ __launch_bounds__(256) void iter2(const float* __restrict__ imfeat,
    const float* __restrict__ centIn, const float* __restrict__ numP,
    const float* __restrict__ denP, float* __restrict__ numO,
    float* __restrict__ denO, float* __restrict__ affO) {
  const int cx = blockIdx.x, cy = blockIdx.y, b = blockIdx.z;
  const int tid = threadIdx.x;
  __shared__ float sc[9][10];
  __shared__ float nb[9][11];
  if (centIn) {
    if (tid < 90) {
      int s = tid / 10, ch = tid - s * 10;
      int dr = s / 3 - 1, dc = s % 3 - 1;
      int r = min(max(cy + dr, 0), 15), c = min(max(cx + dc, 0), 15);
      sc[s][ch] = centIn[((b * 10 + ch) * 16 + r) * 16 + c];
    }
    __syncthreads();
  } else {
    if (tid < 99) {
      int s = tid / 11, j = tid - s * 11;
      int dr = s / 3 - 1, dc = s % 3 - 1;
      int r = min(max(cy + dr, 0), 15), c = min(max(cx + dc, 0), 15);
      float a = 0.f;
      #pragma unroll
      for (int rr = -1; rr <= 1; ++rr)
        #pragma unroll
        for (int cc = -1; cc <= 1; ++cc) {
          int R = r + rr, C = c + cc;
          if ((unsigned)R < 16u && (unsigned)C < 16u)
            a += (j < 10) ? numP[((b * 10 + j) * 16 + R) * 16 + C]
                          : denP[(b * 16 + R) * 16 + C];
        }
      nb[s][j] = a;
    }
    __syncthreads();
    if (tid < 90) {
      int s = tid / 10, ch = tid - s * 10;
      sc[s][ch] = nb[s][ch] / nb[s][10];
    }
    __syncthreads();
  }

  float accN[10];
  #pragma unroll
  for (int ch = 0; ch < 10; ++ch) accN[ch] = 0.f;
  float accD = 0.f;
  const int col = tid & 31, row0 = tid >> 5;
  for (int p = 0; p < 4; ++p) {
    const int y = cy * 32 + row0 + p * 8;
    const int x = cx * 32 + col;
    float f[10];
    #pragma unroll
    for (int ch = 0; ch < 10; ++ch)
      f[ch] = imfeat[((b * 10 + ch) * HH + y) * WW + x];
    float asum = 0.f;
    #pragma unroll
    for (int s = 0; s < 9; ++s) {
      float ss = 0.f;
      #pragma unroll
      for (int ch = 0; ch < 10; ++ch) { float d = f[ch] - sc[s][ch]; ss = fmaf(d, d, ss); }
      float a = __expf(-ss * (1.0f / 1000.0f));
      asum += a;
      if (affO) affO[((b * 9 + s) * HH + y) * WW + x] = a;
    }
    accD += asum;
    #pragma unroll
    for (int ch = 0; ch < 10; ++ch) accN[ch] = fmaf(f[ch], asum, accN[ch]);
  }
  #pragma unroll
  for (int off = 32; off; off >>= 1) {
    accD += __shfl_down(accD, off);
    #pragma unroll
    for (int ch = 0; ch < 10; ++ch) accN[ch] += __shfl_down(accN[ch], off);
  }
  __shared__ float sPart[4][11];
  const int wave = tid >> 6, lane = tid & 63;
  if (lane == 0) {
    #pragma unroll
    for (int ch = 0; ch < 10; ++ch) sPart[wave][ch] = accN[ch];
    sPart[wave][10] = accD;
  }
  __syncthreads();
  if (tid < 11) {
    float s = sPart[0][tid] + sPart[1][tid] + sPart[2][tid] + sPart[3][tid];
    if (tid < 10) numO[((b * 10 + tid) * 16 + cy) * 16 + cx] = s;
    else denO[(b * 16 + cy) * 16 + cx] = s;
  }
}

// ------------------------------- final cent = box3(num)/box3(den) -> output
__global__ __launch_bounds__(256) void cent_final(const float* __restrict__ num_bs,
    const float* __restrict__ den_bs, float* __restrict__ out_cent) {
  const int b = blockIdx.x;
  const int tid = threadIdx.x;
  const int cy = tid >> 4, cx = tid & 15;
  float den = 0.f;
  #pragma unroll
  for (int dr = -1; dr <= 1; ++dr)
    #pragma unroll
    for (int dc = -1; dc <= 1; ++dc) {
      int r = cy + dr, c = cx + dc;
      if ((unsigned)r < 16 && (unsigned)c < 16) den += den_bs[(b * 16 + r) * 16 + c];
    }
  #pragma unroll
  for (int ch = 0; ch < 10; ++ch) {
    float num = 0.f;
    #pragma unroll
    for (int dr = -1; dr <= 1; ++dr)
      #pragma unroll
      for (int dc = -1; dc <= 1; ++dc) {
        int r = cy + dr, c = cx + dc;
        if ((unsigned)r < 16 && (unsigned)c < 16)
          num += num_bs[((b * 10 + ch) * 16 + r) * 16 + c];
      }
    float invck = (ch >= 8) ? (1.0f / CKXY) : 1.0f;
    out_cent[((b * 10 + ch) * 16 + cy) * 16 + cx] = (num / den) * invck;
  }
}

// ---------------------------------------------------------------------------
extern "C" void kernel_launch(void* const* d_in, const int* in_sizes, int n_in,
                              void* d_out, int out_size, void* d_ws, size_t ws_size,
                              hipStream_t stream) {
  const float* X      = (const float*)d_in[0];
  const float* w0     = (const float*)d_in[1];
  const float* b0     = (const float*)d_in[2];
  const float* ws_mid = (const float*)d_in[3];
  const float* bs_mid = (const float*)d_in[4];
  const float* wf     = (const float*)d_in[5];
  const float* bf     = (const float*)d_in[6];
  float* out = (float*)d_out;

  const size_t plane = (size_t)BB * 10 * HW;  // 5,242,880 floats
  float* bufA  = (float*)d_ws;
  float* bufB  = bufA + plane;
  float* num0  = bufB + plane;
  float* den0  = num0 + BB * 10 * 256;
  float* num1  = den0 + BB * 256;
  float* den1  = num1 + BB * 10 * 256;
  float* centA = den1 + BB * 256;

  dim3 cgrid(16, 16, BB);
  conv3x3_t32<3, 10, true><<<cgrid, 256, 0, stream>>>(X, w0, b0, bufA);
  const float* cur = bufA;
  float* nxt = bufB;
  for (int l = 0; l < 8; ++l) {
    conv3x3_t32<10, 10, true><<<cgrid, 256, 0, stream>>>(cur, ws_mid + l * 900, bs_mid + l * 10, nxt);
    const float* t = cur; cur = nxt; nxt = (float*)t;
  }
  // cur == bufA after 8 swaps; imfeat -> bufB, cent0 -> centA
  conv_final_t32<<<cgrid, 256, 0, stream>>>(cur, wf, bf, X, bufB, centA);

  float* aff_out = out + BB * 10 * 256;  // cent (5120) then aff
  float* nums[2] = {num0, num1};
  float* dens[2] = {den0, den1};
  for (int k = 0; k < 10; ++k) {
    iter2<<<cgrid, 256, 0, stream>>>(bufB,
        (k == 0) ? centA : nullptr,
        (k == 0) ? nullptr : nums[(k - 1) & 1],
        (k == 0) ? nullptr : dens[(k - 1) & 1],
        nums[k & 1], dens[k & 1],
        (k == 9) ? aff_out : nullptr);
  }
  cent_final<<<dim3(BB), 256, 0, stream>>>(nums[1], dens[1], out);
}